// Round 10
// baseline (118.436 us; speedup 1.0000x reference)
//
#include <hip/hip_runtime.h>

#define LNUM 12
#define TNUM 12
#define NPASS 7   // 1 initial pass + HORIZON=6
#define GL 6      // layers per group (2 groups)
#define CPB 64    // chains per block (one wave per group)

// ---------------------------------------------------------------------------
// Prep kernel (validated in round 7): pre-scale weights/biases once into d_ws.
//   [0..11] wi0' [12..23] wi1' [24..35] wi2' [36..47] wh0' [48..59] wh1'
//   [60..71] wh2' [72..83] b0' [84..95] b1' [96..107] bi2' [108..119] bh2'
// Gates r,z scaled by -log2(e); gate n scaled by 2*log2(e).
// ---------------------------------------------------------------------------
__global__ void gru_prep_kernel(const float* __restrict__ w_ih,
                                const float* __restrict__ w_hh,
                                const float* __restrict__ b_ih,
                                const float* __restrict__ b_hh,
                                float* __restrict__ ws) {
    const float NL2E = -1.4426950408889634f;
    const float TL2E =  2.8853900817779268f;
    int j = threadIdx.x;
    if (j >= 10 * LNUM) return;
    int g = j / LNUM, l = j % LNUM;
    float v;
    switch (g) {
        case 0: v = NL2E * w_ih[3*l+0]; break;
        case 1: v = NL2E * w_ih[3*l+1]; break;
        case 2: v = TL2E * w_ih[3*l+2]; break;
        case 3: v = NL2E * w_hh[3*l+0]; break;
        case 4: v = NL2E * w_hh[3*l+1]; break;
        case 5: v = TL2E * w_hh[3*l+2]; break;
        case 6: v = NL2E * (b_ih[3*l+0] + b_hh[3*l+0]); break;
        case 7: v = NL2E * (b_ih[3*l+1] + b_hh[3*l+1]); break;
        case 8: v = TL2E * b_ih[3*l+2]; break;
        default: v = TL2E * b_hh[3*l+2]; break;
    }
    ws[j] = v;
}

// Load this group's 24 biases and pin them into VGPRs (asm blocks scalar
// rematerialization -> no per-use v_mov from double-SGPR operands; r7 lesson).
template<int BASE>
__device__ __forceinline__ void load_bias(const float* __restrict__ ws,
                                          float (&bias)[4 * GL]) {
#pragma unroll
    for (int i = 0; i < GL; ++i) {
        float b0  = ws[72  + BASE + i];
        float b1  = ws[84  + BASE + i];
        float bi2 = ws[96  + BASE + i];
        float bh2 = ws[108 + BASE + i];
        asm volatile("" : "+v"(b0), "+v"(b1), "+v"(bi2), "+v"(bh2));
        bias[4*i+0] = b0; bias[4*i+1] = b1; bias[4*i+2] = bi2; bias[4*i+3] = bh2;
    }
}

// One time-step through this group's 6 layers. Weights: compile-time offsets
// -> uniform s_loads (SGPR, LICM'd); biases: VGPR; h: static-indexed regs.
// Per layer: 16 VALU + 5 trans (shared-rcp double sigmoid, validated r7).
template<int BASE>
__device__ __forceinline__ float step6(const float* __restrict__ ws,
                                       const float (&bias)[4 * GL],
                                       float (&h)[GL], float inp) {
#pragma unroll
    for (int i = 0; i < GL; ++i) {
        const float wi0 = ws[ 0 + BASE + i];
        const float wi1 = ws[12 + BASE + i];
        const float wi2 = ws[24 + BASE + i];
        const float wh0 = ws[36 + BASE + i];
        const float wh1 = ws[48 + BASE + i];
        const float wh2 = ws[60 + BASE + i];

        float ar = fmaf(inp, wi0, fmaf(h[i], wh0, bias[4*i+0]));
        float az = fmaf(inp, wi1, fmaf(h[i], wh1, bias[4*i+1]));
        float gn = fmaf(inp, wi2, bias[4*i+2]);
        float hg = fmaf(h[i], wh2, bias[4*i+3]);

        float er = __builtin_amdgcn_exp2f(ar);
        float ez = __builtin_amdgcn_exp2f(az);
        float ea = 1.0f + er;
        float eb = 1.0f + ez;
        float D  = __builtin_amdgcn_rcpf(ea * eb);  // one rcp, two sigmoids
        float r  = D * eb;
        float z  = D * ea;

        float en = __builtin_amdgcn_exp2f(fmaf(r, hg, gn));
        float u  = __builtin_amdgcn_rcpf(1.0f + en);
        float n  = fmaf(-2.0f, u, 1.0f);            // tanh

        float hn = fmaf(z, h[i], fmaf(-z, n, n));   // (1-z)n + z*h
        h[i] = hn;
        inp  = hn;
    }
    return inp;
}

// ---------------------------------------------------------------------------
// 2-stage systolic pipeline. Wave 0 (lanes 0-63 of block) = layers 0-5,
// wave 1 = layers 6-11, skewed by one t-step. Handoff h5 via hand[2] (ping-
// pong on t&1); top-layer output feeds next pass's layer 0 via ring[t].
// Schedule: iter (p,t): g0 computes (p,t); g1 computes (p,t-1) [t-1<0 ->
// (p-1,11)]. 84 iters + 1 epilogue step, one barrier per iteration.
// ---------------------------------------------------------------------------
__global__ __launch_bounds__(128, 2)
void gru_sys_kernel(const float* __restrict__ x,
                    const float* __restrict__ ws,
                    float* __restrict__ out,
                    int total) {
    __shared__ float ring[TNUM][CPB];  // ring[t] = g1 top output for time t
    __shared__ float hand[2][CPB];     // g0 h5 output, ping-pong by t&1

    const int  lane  = threadIdx.x & 63;
    const bool g0    = threadIdx.x < 64;
    const int  chain = blockIdx.x * CPB + lane;

    float h[GL];
#pragma unroll
    for (int i = 0; i < GL; ++i) h[i] = 0.0f;

    float bias[4 * GL];
    float seq[TNUM];
    if (g0) {
        load_bias<0>(ws, bias);
        const float4* xv = reinterpret_cast<const float4*>(x + (size_t)chain * TNUM);
#pragma unroll
        for (int i = 0; i < TNUM / 4; ++i) {
            float4 v = xv[i];
            seq[i*4+0] = v.x; seq[i*4+1] = v.y; seq[i*4+2] = v.z; seq[i*4+3] = v.w;
        }
    } else {
        load_bias<GL>(ws, bias);
    }

#pragma unroll 1
    for (int p = 0; p < NPASS; ++p) {
#pragma unroll
        for (int t = 0; t < TNUM; ++t) {
            if (g0) {
                // input: pass 0 -> x stream (regs); else g1's time-t output
                // of pass p-1, written at iter (p-1,t+1) / (p,0).
                float inp = (p == 0) ? seq[t] : ring[t][lane];
                float h5  = step6<0>(ws, bias, h, inp);
                hand[t & 1][lane] = h5;
            } else {
                if (t > 0 || p > 0) {   // g1 idle only at iter (0,0)
                    // g1 processes time t-1 (t=0 -> time 11 of pass p-1):
                    // input written by g0 at prev iter into hand[(t-1)&1].
                    float inp = hand[(t + 1) & 1][lane];
                    float top = step6<GL>(ws, bias, h, inp);
                    ring[(t + 11) % 12][lane] = top;  // slot = its time index
                }
            }
            __syncthreads();
        }
    }
    // Epilogue: g1's last step (time 11 of pass 6); input written by g0 at
    // iter (6,11) into hand[1]; loop's final barrier made it visible.
    if (!g0) {
        float inp = hand[1][lane];
        (void)step6<GL>(ws, bias, h, inp);
    }

    const int base_l = g0 ? 0 : GL;
#pragma unroll
    for (int i = 0; i < GL; ++i) {
        out[(size_t)(base_l + i) * total + chain] = h[i];
    }
}

extern "C" void kernel_launch(void* const* d_in, const int* in_sizes, int n_in,
                              void* d_out, int out_size, void* d_ws, size_t ws_size,
                              hipStream_t stream) {
    const float* x    = (const float*)d_in[0];
    const float* w_ih = (const float*)d_in[1];
    const float* w_hh = (const float*)d_in[2];
    const float* b_ih = (const float*)d_in[3];
    const float* b_hh = (const float*)d_in[4];
    float* out = (float*)d_out;
    float* ws  = (float*)d_ws;

    gru_prep_kernel<<<1, 128, 0, stream>>>(w_ih, w_hh, b_ih, b_hh, ws);

    const int total = in_sizes[0] / TNUM;        // B*N = 65536 chains
    const int grid  = total / CPB;               // 1024 blocks of 128 threads
    gru_sys_kernel<<<grid, 128, 0, stream>>>(x, ws, out, total);
}

// Round 11
// 110.544 us; speedup vs baseline: 1.0714x; 1.0714x over previous
//
#include <hip/hip_runtime.h>

#define LNUM 12
#define TNUM 12
#define NPASS 7   // 1 initial pass + HORIZON=6

// ---------------------------------------------------------------------------
// Prep kernel (validated r7): pre-scale weights/biases once into d_ws.
// ws layout, [group*12 + layer], groups:
//   0: wi0' = -log2e*w_ih[l][0]   1: wi1' = -log2e*w_ih[l][1]
//   2: wi2' =  2log2e*w_ih[l][2]  3: wh0' = -log2e*w_hh[l][0]
//   4: wh1' = -log2e*w_hh[l][1]   5: wh2' =  2log2e*w_hh[l][2]
//   6: b0'  = -log2e*(b_ih0+b_hh0) 7: b1' = -log2e*(b_ih1+b_hh1)
//   8: bi2' =  2log2e*b_ih[l][2]  9: bh2' = 2log2e*b_hh[l][2]
// ---------------------------------------------------------------------------
__global__ void gru_prep_kernel(const float* __restrict__ w_ih,
                                const float* __restrict__ w_hh,
                                const float* __restrict__ b_ih,
                                const float* __restrict__ b_hh,
                                float* __restrict__ ws) {
    const float NL2E = -1.4426950408889634f;
    const float TL2E =  2.8853900817779268f;
    int j = threadIdx.x;
    if (j >= 10 * LNUM) return;
    int g = j / LNUM, l = j % LNUM;
    float v;
    switch (g) {
        case 0: v = NL2E * w_ih[3*l+0]; break;
        case 1: v = NL2E * w_ih[3*l+1]; break;
        case 2: v = TL2E * w_ih[3*l+2]; break;
        case 3: v = NL2E * w_hh[3*l+0]; break;
        case 4: v = NL2E * w_hh[3*l+1]; break;
        case 5: v = TL2E * w_hh[3*l+2]; break;
        case 6: v = NL2E * (b_ih[3*l+0] + b_hh[3*l+0]); break;
        case 7: v = NL2E * (b_ih[3*l+1] + b_hh[3*l+1]); break;
        case 8: v = TL2E * b_ih[3*l+2]; break;
        default: v = TL2E * b_hh[3*l+2]; break;
    }
    ws[j] = v;
}

// One GRU cell for layer l (compile-time). Reads pre-diagonal h[l] and inp,
// writes h[l]. 14 VALU + 5 trans (shared-rcp double sigmoid, validated r7).
__device__ __forceinline__ float cell(const float (&W)[10][LNUM],
                                      float (&h)[LNUM], const int l, float inp) {
    float ar = fmaf(inp,  W[0][l], fmaf(h[l], W[3][l], W[6][l]));
    float az = fmaf(inp,  W[1][l], fmaf(h[l], W[4][l], W[7][l]));
    float gn = fmaf(inp,  W[2][l], W[8][l]);
    float hg = fmaf(h[l], W[5][l], W[9][l]);

    float er = __builtin_amdgcn_exp2f(ar);
    float ez = __builtin_amdgcn_exp2f(az);
    float ea = 1.0f + er;
    float eb = 1.0f + ez;
    float D  = __builtin_amdgcn_rcpf(ea * eb);   // one rcp -> both sigmoids
    float r  = D * eb;
    float z  = D * ea;

    float en = __builtin_amdgcn_exp2f(fmaf(r, hg, gn));
    float u  = __builtin_amdgcn_rcpf(1.0f + en);
    float n  = fmaf(-2.0f, u, 1.0f);             // tanh

    float hn = fmaf(z, h[l], fmaf(-z, n, n));    // (1-z)n + z*h
    h[l] = hn;
    return hn;
}

// ---------------------------------------------------------------------------
// Diagonal-wavefront kernel: one thread per chain; cells (p,t,l) executed by
// diagonal d = 12p + t + l. Steady state = 12 independent cells/diagonal
// (12-way ILP inside the thread -> dependency latency self-hidden; no LDS,
// no barriers). In-place on h[12], descending l (reads pre-diagonal values).
// Slot 0 input: seq[d] while p==0 (prologue), else old h[11] (= prev pass
// top output at same t, produced at diagonal d-1). 1008 cells total.
// ---------------------------------------------------------------------------
__global__ __launch_bounds__(256, 1)
void gru_diag_kernel(const float* __restrict__ x,
                     const float* __restrict__ ws,
                     float* __restrict__ out,
                     int total) {
    const int tid = blockIdx.x * blockDim.x + threadIdx.x;
    if (tid >= total) return;

    // All 120 pre-scaled uniforms pinned to VGPRs: SGPR budget (102) cannot
    // hold them, and letting them fall back to per-use memory reloads was the
    // r7/r10 failure. 1 wave/SIMD + launch_bounds(256,1) -> 512-VGPR budget.
    float W[10][LNUM];
#pragma unroll
    for (int g = 0; g < 10; ++g) {
#pragma unroll
        for (int l = 0; l < LNUM; ++l) {
            float w = ws[g * LNUM + l];
            asm volatile("" : "+v"(w));
            W[g][l] = w;
        }
    }

    // This chain's 12 inputs (contiguous 48B -> 3x float4).
    float seq[TNUM];
    const float4* xv = reinterpret_cast<const float4*>(x + (size_t)tid * TNUM);
#pragma unroll
    for (int i = 0; i < TNUM / 4; ++i) {
        float4 v = xv[i];
        seq[i*4+0] = v.x; seq[i*4+1] = v.y; seq[i*4+2] = v.z; seq[i*4+3] = v.w;
    }

    float h[LNUM];
#pragma unroll
    for (int l = 0; l < LNUM; ++l) h[l] = 0.0f;

    // ---- Prologue: d = 0..11 (slot l active iff l <= d; slot 0 reads seq[d],
    // since p==0 exactly while d<12). Fully unrolled -> compile-time preds.
#pragma unroll
    for (int d = 0; d < 12; ++d) {
#pragma unroll
        for (int l = 11; l >= 1; --l) {
            if (l <= d) h[l] = cell(W, h, l, h[l - 1]);
        }
        h[0] = cell(W, h, 0, seq[d]);
    }

    // ---- Main: d = 12..83, all 12 slots active. top = pre-diagonal h[11]
    // = prev-pass top output at this slot-0 cell's t (produced at d-1).
#pragma unroll 1
    for (int d = 12; d < 84; ++d) {
        float top = h[11];
#pragma unroll
        for (int l = 11; l >= 1; --l) {
            h[l] = cell(W, h, l, h[l - 1]);
        }
        h[0] = cell(W, h, 0, top);
    }

    // ---- Epilogue: d = 84..94 (slot l active iff l >= d-83; slot 0 done).
#pragma unroll
    for (int d = 84; d < 95; ++d) {
#pragma unroll
        for (int l = 11; l >= 1; --l) {
            if (l >= d - 83) h[l] = cell(W, h, l, h[l - 1]);
        }
    }

    // h[l] now holds the final hidden state of layer l (cell (6,11,l)).
#pragma unroll
    for (int l = 0; l < LNUM; ++l) {
        out[(size_t)l * total + tid] = h[l];
    }
}

extern "C" void kernel_launch(void* const* d_in, const int* in_sizes, int n_in,
                              void* d_out, int out_size, void* d_ws, size_t ws_size,
                              hipStream_t stream) {
    const float* x    = (const float*)d_in[0];
    const float* w_ih = (const float*)d_in[1];
    const float* w_hh = (const float*)d_in[2];
    const float* b_ih = (const float*)d_in[3];
    const float* b_hh = (const float*)d_in[4];
    float* out = (float*)d_out;
    float* ws  = (float*)d_ws;

    gru_prep_kernel<<<1, 128, 0, stream>>>(w_ih, w_hh, b_ih, b_hh, ws);

    const int total = in_sizes[0] / TNUM;   // B*N = 65536 chains
    const int block = 256;
    const int grid  = (total + block - 1) / block;
    gru_diag_kernel<<<grid, block, 0, stream>>>(x, ws, out, total);
}